// Round 17
// baseline (71.859 us; speedup 1.0000x reference)
//
#include <hip/hip_runtime.h>

// ---------------------------------------------------------------------------
// TreeEncoder, round 17 = round 16 (8-wave-rung, 52.5us kernel) with:
//   1) double-buffered weight staging -> ONE barrier per step (was 2).
//      Stage for step S+1 issues at the TOP of step S into the other buffer:
//      full-step latency cover; the end-of-step barrier (vmcnt+lgkm drain)
//      fences both the staged data and the buffer swap.
//   2) msum[8] in registers (constexpr-indexed, fully unrolled) -- removes
//      per-step shuffle-reduce + LDS write.
//   3) LDS 31.7 KB -> 5 blocks/CU (20 waves); bet: 16 looser barriers beat
//      r16's 32 tight ones at ~equal effective occupancy (~60% measured).
// ---------------------------------------------------------------------------

typedef short bf16x8 __attribute__((ext_vector_type(8)));
typedef float f32x4  __attribute__((ext_vector_type(4)));

#define MFMA16(a, b, c) __builtin_amdgcn_mfma_f32_16x16x32_bf16((a), (b), (c), 0, 0, 0)

#define NEG_L2E (-1.44269504088896f)
#define TWO_L2E (2.88539008177793f)

__device__ __forceinline__ unsigned short f2bf(float f) {
    return (unsigned short)((__float_as_uint(f) + 0x8000u) >> 16);
}
__device__ __forceinline__ float frcp(float x)  { return __builtin_amdgcn_rcpf(x); }
__device__ __forceinline__ float fexp2(float x) { return __builtin_amdgcn_exp2f(x); }

// Pade[3/2] merged activation (r11 numerics): pre-scaled logits
__device__ __forceinline__ float act_h(float iv, float ov, float cv) {
    float ei = fexp2(iv);
    float eo = fexp2(ov);
    float u  = fexp2(cv);
    float p  = u - 1.0f;
    float q  = (1.0f + ei) * (u + 1.0f);     // cc = p/q = sig(i)*tanh(c~)
    float p2 = p * p, q2 = q * q;
    float t15 = 15.0f * q2;
    return (p * (t15 + p2)) * frcp((q * (6.0f * p2 + t15)) * (1.0f + eo));
}

__device__ __forceinline__ bf16x8 pack8(float4 v0, float4 v1) {
    bf16x8 a;
    a[0] = (short)f2bf(v0.x); a[1] = (short)f2bf(v0.y);
    a[2] = (short)f2bf(v0.z); a[3] = (short)f2bf(v0.w);
    a[4] = (short)f2bf(v1.x); a[5] = (short)f2bf(v1.y);
    a[6] = (short)f2bf(v1.z); a[7] = (short)f2bf(v1.w);
    return a;
}

// async global->LDS, 16B/lane; LDS dest = wave-uniform base + lane*16
__device__ __forceinline__ void gload_lds16(const void* gsrc, void* ldst) {
    __builtin_amdgcn_global_load_lds(
        (const __attribute__((address_space(1))) unsigned int*)gsrc,
        (__attribute__((address_space(3))) unsigned int*)ldst, 16, 0, 0);
}

// ---------------------------------------------------------------------------
// Prep (53 blocks x 256): ws layout identical to rounds 8-16.
//   [0,16384) emb frags; [16384,212992) gate frags; [212992,216064) biases.
// ---------------------------------------------------------------------------
__global__ void prep_frags(const float* __restrict__ embW,
                           const float* __restrict__ Wi,
                           const float* __restrict__ Wo,
                           const float* __restrict__ Wc,
                           const float* __restrict__ bWi, const float* __restrict__ bUi,
                           const float* __restrict__ bWo, const float* __restrict__ bUo,
                           const float* __restrict__ bWc, const float* __restrict__ bUc,
                           char* __restrict__ ws) {
    const int tid = threadIdx.x;
    const int fb  = blockIdx.x * 4 + (tid >> 6);
    const int l   = tid & 63;

    if (fb < 208) {
        int g  = l >> 4, c0 = l & 15;
        const float* src;
        int t, kk;
        size_t dst;
        float scale;
        if (fb < 16) {
            t = fb >> 1; kk = fb & 1;
            src = embW;                                   // [64][128]
            dst = (size_t)fb * 1024;
            scale = 1.0f;
        } else {
            int r = fb - 16;                              // (layer*8+t)*12+gate*4+kk
            int layer = r / 96;
            int r2 = r % 96;
            t = r2 / 12;
            int r3 = r2 % 12;
            int gate = r3 >> 2;
            kk = r3 & 3;
            const float* Ws[3] = {Wi, Wo, Wc};
            src = Ws[gate] + (size_t)layer * 128 * 128;   // [128][128]
            dst = 16384 + (size_t)r * 1024;
            scale = (gate == 2) ? TWO_L2E : NEG_L2E;
        }
        bf16x8 v;
#pragma unroll
        for (int e = 0; e < 8; ++e) {
            int k   = kk * 32 + g * 8 + e;
            int col = t * 16 + c0;
            v[e] = (short)f2bf(scale * src[(size_t)k * 128 + col]);
        }
        *reinterpret_cast<bf16x8*>(ws + dst + (size_t)l * 16) = v;
    } else if (blockIdx.x == 52) {
        float* bias = reinterpret_cast<float*>(ws + 212992);
#pragma unroll
        for (int j = 0; j < 3; ++j) {
            int v = j * 256 + tid;              // 0..767
            int layer = v / 384;
            int r = v % 384;
            int gate = r >> 7;
            int c = r & 127;
            int idx = layer * 128 + c;
            float x;
            if (gate == 0)      x = NEG_L2E * (bWi[idx] + bUi[idx]);
            else if (gate == 1) x = NEG_L2E * (bWo[idx] + bUo[idx]);
            else                x = TWO_L2E * (bWc[idx] + bUc[idx]);
            bias[v] = x;
        }
    }
}

// ---------------------------------------------------------------------------
// One step (L = S>>3, T = S&7).  Per step:
//   issue async stage of S+1 into the OTHER buffer -> per-gate MFMA from the
//   CURRENT buffer -> activation (covers staging latency) -> ONE barrier.
// ---------------------------------------------------------------------------
template<int S>
__device__ __forceinline__ void t_step(
        char* __restrict__ sb0, char* __restrict__ sb1,
        const char* __restrict__ frags,
        bf16x8 (&A0)[4], bf16x8 (&A1)[4],
        unsigned short* __restrict__ slab,
        const float* __restrict__ biasf,
        float (&msum)[8],
        int w, int l, int g, int c0) {

    constexpr int L = S >> 3;
    constexpr int T = S & 7;
    char* cur = (S & 1) ? sb1 : sb0;
    char* nxt = (S & 1) ? sb0 : sb1;

    // stage S+1 at top: the whole step (MFMA + act) hides its latency.
    // nxt was last READ at step S-1, fenced by that step's barrier.
    if constexpr (S < 15) {
        const char* gs = frags + 16384 + (size_t)(S + 1) * 12288;
#pragma unroll
        for (int i = 0; i < 3; ++i)
            gload_lds16(gs + (size_t)(i * 4096 + w * 1024) + (size_t)l * 16,
                        nxt + i * 4096 + w * 1024);
    }

    const int c = T * 16 + c0;
    const float Bi = biasf[L * 384 + c];
    const float Bo = biasf[L * 384 + 128 + c];
    const float Bc = biasf[L * 384 + 256 + c];

    const bf16x8 (&A)[4] = (L == 0) ? A0 : A1;
    const char* sr = cur + (size_t)l * 16;

    f32x4 ai = {Bi, Bi, Bi, Bi};
    f32x4 ao = {Bo, Bo, Bo, Bo};
    f32x4 ac = {Bc, Bc, Bc, Bc};
    // per-gate loops: transient weight regs stay tiny (64-reg rung)
#pragma unroll
    for (int kk = 0; kk < 4; ++kk)
        ac = MFMA16(A[kk], *reinterpret_cast<const bf16x8*>(sr + (size_t)(8 + kk) * 1024), ac);
#pragma unroll
    for (int kk = 0; kk < 4; ++kk)
        ai = MFMA16(A[kk], *reinterpret_cast<const bf16x8*>(sr + (size_t)(0 + kk) * 1024), ai);
#pragma unroll
    for (int kk = 0; kk < 4; ++kk)
        ao = MFMA16(A[kk], *reinterpret_cast<const bf16x8*>(sr + (size_t)(4 + kk) * 1024), ao);

    // activation (registers only)
#pragma unroll
    for (int r = 0; r < 4; ++r) {
        float h = act_h(ai[r], ao[r], ac[r]);
        if constexpr (L == 1) {
            msum[T] += h;                                   // constexpr index
        } else {
            slab[(g * 4 + r) * 40 + (T & 1) * 16 + c0] = f2bf(h);
        }
    }
    if constexpr (L == 0 && (T & 1) == 1)   // pair complete -> A1 frag (wave-private DS)
        A1[T >> 1] = *reinterpret_cast<const bf16x8*>(&slab[c0 * 40 + g * 8]);

    __syncthreads();   // drains gload (vmcnt) + fences buffer swap
}

// ---------------------------------------------------------------------------
// Main kernel: 2048 blocks x 256 threads; 16 rows/wave; 16 barriers total.
// ---------------------------------------------------------------------------
__global__ __launch_bounds__(256, 8) void tree_enc(
        const float* __restrict__ X,       // [131072][64]
        const float* __restrict__ emb_b,   // [128]
        const char*  __restrict__ frags,   // ws
        float* __restrict__ out) {         // [256][128]

    __shared__ __align__(16) char sbuf0[12288];                // 12288 B
    __shared__ __align__(16) char sbuf1[12288];                // 12288 B
    __shared__ __align__(16) unsigned short slabs[4][16 * 40]; //  5120 B
    __shared__ float redbuf[4][128];                           //  2048 B

    const int tid = threadIdx.x;
    const int w   = tid >> 6;
    const int l   = tid & 63;
    const int g   = l >> 4;
    const int c0  = l & 15;
    const int rowbase = blockIdx.x * 64 + w * 16;
    const int batch   = blockIdx.x >> 3;        // 8 blocks per batch

    unsigned short* __restrict__ slab = slabs[w];
    const float* biasf = reinterpret_cast<const float*>(frags + 212992);

    // -------- async-stage step 0 weights into sbuf0 (overlaps embedding) --
    {
        const char* gs = frags + 16384;
#pragma unroll
        for (int i = 0; i < 3; ++i)
            gload_lds16(gs + (size_t)(i * 4096 + w * 1024) + (size_t)l * 16,
                        sbuf0 + i * 4096 + w * 1024);
    }

    // -------- embedding: h0 for this wave's 16 rows -> slab -> A0 ----------
    bf16x8 A0[4], A1[4];
    {
        bf16x8 afr0, afr1;
        {
            const float* xr = X + (size_t)(rowbase + c0) * 64;
            float4 v0 = *reinterpret_cast<const float4*>(xr + g * 8);
            float4 v1 = *reinterpret_cast<const float4*>(xr + g * 8 + 4);
            float4 v2 = *reinterpret_cast<const float4*>(xr + 32 + g * 8);
            float4 v3 = *reinterpret_cast<const float4*>(xr + 32 + g * 8 + 4);
            afr0 = pack8(v0, v1);
            afr1 = pack8(v2, v3);
        }
#pragma unroll
        for (int t = 0; t < 8; ++t) {
            const char* eb = frags + (size_t)(t * 2) * 1024 + (size_t)l * 16;
            bf16x8 e0 = *reinterpret_cast<const bf16x8*>(eb);
            bf16x8 e1 = *reinterpret_cast<const bf16x8*>(eb + 1024);
            const float be = emb_b[t * 16 + c0];
            f32x4 acc = {be, be, be, be};
            acc = MFMA16(afr0, e0, acc);
            acc = MFMA16(afr1, e1, acc);
#pragma unroll
            for (int r = 0; r < 4; ++r)
                slab[(g * 4 + r) * 40 + (t & 1) * 16 + c0] = f2bf(acc[r]);
            if (t & 1)
                A0[t >> 1] = *reinterpret_cast<const bf16x8*>(&slab[c0 * 40 + g * 8]);
        }
    }
    __syncthreads();   // embedding done AND step-0 staging drained

    // -------- 16 steps, one barrier each --------
    float msum[8];
#pragma unroll
    for (int t = 0; t < 8; ++t) msum[t] = 0.f;

    t_step< 0>(sbuf0, sbuf1, frags, A0, A1, slab, biasf, msum, w, l, g, c0);
    t_step< 1>(sbuf0, sbuf1, frags, A0, A1, slab, biasf, msum, w, l, g, c0);
    t_step< 2>(sbuf0, sbuf1, frags, A0, A1, slab, biasf, msum, w, l, g, c0);
    t_step< 3>(sbuf0, sbuf1, frags, A0, A1, slab, biasf, msum, w, l, g, c0);
    t_step< 4>(sbuf0, sbuf1, frags, A0, A1, slab, biasf, msum, w, l, g, c0);
    t_step< 5>(sbuf0, sbuf1, frags, A0, A1, slab, biasf, msum, w, l, g, c0);
    t_step< 6>(sbuf0, sbuf1, frags, A0, A1, slab, biasf, msum, w, l, g, c0);
    t_step< 7>(sbuf0, sbuf1, frags, A0, A1, slab, biasf, msum, w, l, g, c0);
    t_step< 8>(sbuf0, sbuf1, frags, A0, A1, slab, biasf, msum, w, l, g, c0);
    t_step< 9>(sbuf0, sbuf1, frags, A0, A1, slab, biasf, msum, w, l, g, c0);
    t_step<10>(sbuf0, sbuf1, frags, A0, A1, slab, biasf, msum, w, l, g, c0);
    t_step<11>(sbuf0, sbuf1, frags, A0, A1, slab, biasf, msum, w, l, g, c0);
    t_step<12>(sbuf0, sbuf1, frags, A0, A1, slab, biasf, msum, w, l, g, c0);
    t_step<13>(sbuf0, sbuf1, frags, A0, A1, slab, biasf, msum, w, l, g, c0);
    t_step<14>(sbuf0, sbuf1, frags, A0, A1, slab, biasf, msum, w, l, g, c0);
    t_step<15>(sbuf0, sbuf1, frags, A0, A1, slab, biasf, msum, w, l, g, c0);

    // -------- wave reduce -> block reduce -> one atomic per column --------
#pragma unroll
    for (int t = 0; t < 8; ++t) {
        float v = msum[t];
        v += __shfl_xor(v, 16);
        v += __shfl_xor(v, 32);
        if (g == 0) redbuf[w][t * 16 + c0] = v;
    }
    __syncthreads();
    if (tid < 128) {
        float s = redbuf[0][tid] + redbuf[1][tid] + redbuf[2][tid] + redbuf[3][tid];
        atomicAdd(&out[batch * 128 + tid], s * (1.0f / 512.0f));
    }
}

// ---------------------------------------------------------------------------
extern "C" void kernel_launch(void* const* d_in, const int* in_sizes, int n_in,
                              void* d_out, int out_size, void* d_ws, size_t ws_size,
                              hipStream_t stream) {
    const float* X    = (const float*)d_in[0];
    const float* embW = (const float*)d_in[1];
    const float* embb = (const float*)d_in[2];
    const float* Wi   = (const float*)d_in[3];
    const float* Wo   = (const float*)d_in[4];
    const float* Wc   = (const float*)d_in[5];
    const float* bWi  = (const float*)d_in[6];
    const float* bUi  = (const float*)d_in[7];
    const float* bWo  = (const float*)d_in[8];
    const float* bUo  = (const float*)d_in[9];
    const float* bWc  = (const float*)d_in[10];
    const float* bUc  = (const float*)d_in[11];
    float* out = (float*)d_out;
    char*  ws  = (char*)d_ws;

    hipMemsetAsync(d_out, 0, (size_t)out_size * sizeof(float), stream);
    prep_frags<<<53, 256, 0, stream>>>(embW, Wi, Wo, Wc,
                                       bWi, bUi, bWo, bUo, bWc, bUc, ws);
    tree_enc<<<2048, 256, 0, stream>>>(X, embb, (const char*)ws, out);
}

// Round 18
// 59.563 us; speedup vs baseline: 1.2064x; 1.2064x over previous
//
#include <hip/hip_runtime.h>

// ---------------------------------------------------------------------------
// TreeEncoder, round 18 = round 16 (52.5us kernel, VGPR=32, 8-wave rung)
// with ONE isolated change: double-buffered weight staging -> one barrier
// per step (16 total, was 32).  Stage for S+1 issues at the TOP of step S
// into the other buffer (full-step latency cover); the end-of-step barrier
// (vmcnt drain) fences staged data + buffer swap.
//   r17 bundled this with msum->registers and VGPR exploded 32->100
//   (4-wave rung, 68.6us).  This round keeps r16's register-lean body:
//   slab-sunk A-frags, per-step shuffle-reduce -> redbuf, no persistent
//   msum registers.
// ---------------------------------------------------------------------------

typedef short bf16x8 __attribute__((ext_vector_type(8)));
typedef float f32x4  __attribute__((ext_vector_type(4)));

#define MFMA16(a, b, c) __builtin_amdgcn_mfma_f32_16x16x32_bf16((a), (b), (c), 0, 0, 0)

#define NEG_L2E (-1.44269504088896f)
#define TWO_L2E (2.88539008177793f)

__device__ __forceinline__ unsigned short f2bf(float f) {
    return (unsigned short)((__float_as_uint(f) + 0x8000u) >> 16);
}
__device__ __forceinline__ float frcp(float x)  { return __builtin_amdgcn_rcpf(x); }
__device__ __forceinline__ float fexp2(float x) { return __builtin_amdgcn_exp2f(x); }

// Pade[3/2] merged activation (r11 numerics): pre-scaled logits
__device__ __forceinline__ float act_h(float iv, float ov, float cv) {
    float ei = fexp2(iv);
    float eo = fexp2(ov);
    float u  = fexp2(cv);
    float p  = u - 1.0f;
    float q  = (1.0f + ei) * (u + 1.0f);     // cc = p/q = sig(i)*tanh(c~)
    float p2 = p * p, q2 = q * q;
    float t15 = 15.0f * q2;
    return (p * (t15 + p2)) * frcp((q * (6.0f * p2 + t15)) * (1.0f + eo));
}

__device__ __forceinline__ bf16x8 pack8(float4 v0, float4 v1) {
    bf16x8 a;
    a[0] = (short)f2bf(v0.x); a[1] = (short)f2bf(v0.y);
    a[2] = (short)f2bf(v0.z); a[3] = (short)f2bf(v0.w);
    a[4] = (short)f2bf(v1.x); a[5] = (short)f2bf(v1.y);
    a[6] = (short)f2bf(v1.z); a[7] = (short)f2bf(v1.w);
    return a;
}

// async global->LDS, 16B/lane; LDS dest = wave-uniform base + lane*16
__device__ __forceinline__ void gload_lds16(const void* gsrc, void* ldst) {
    __builtin_amdgcn_global_load_lds(
        (const __attribute__((address_space(1))) unsigned int*)gsrc,
        (__attribute__((address_space(3))) unsigned int*)ldst, 16, 0, 0);
}

// ---------------------------------------------------------------------------
// Prep (53 blocks x 256): ws layout identical to rounds 8-17.
//   [0,16384) emb frags; [16384,212992) gate frags; [212992,216064) biases.
// ---------------------------------------------------------------------------
__global__ void prep_frags(const float* __restrict__ embW,
                           const float* __restrict__ Wi,
                           const float* __restrict__ Wo,
                           const float* __restrict__ Wc,
                           const float* __restrict__ bWi, const float* __restrict__ bUi,
                           const float* __restrict__ bWo, const float* __restrict__ bUo,
                           const float* __restrict__ bWc, const float* __restrict__ bUc,
                           char* __restrict__ ws) {
    const int tid = threadIdx.x;
    const int fb  = blockIdx.x * 4 + (tid >> 6);
    const int l   = tid & 63;

    if (fb < 208) {
        int g  = l >> 4, c0 = l & 15;
        const float* src;
        int t, kk;
        size_t dst;
        float scale;
        if (fb < 16) {
            t = fb >> 1; kk = fb & 1;
            src = embW;                                   // [64][128]
            dst = (size_t)fb * 1024;
            scale = 1.0f;
        } else {
            int r = fb - 16;                              // (layer*8+t)*12+gate*4+kk
            int layer = r / 96;
            int r2 = r % 96;
            t = r2 / 12;
            int r3 = r2 % 12;
            int gate = r3 >> 2;
            kk = r3 & 3;
            const float* Ws[3] = {Wi, Wo, Wc};
            src = Ws[gate] + (size_t)layer * 128 * 128;   // [128][128]
            dst = 16384 + (size_t)r * 1024;
            scale = (gate == 2) ? TWO_L2E : NEG_L2E;
        }
        bf16x8 v;
#pragma unroll
        for (int e = 0; e < 8; ++e) {
            int k   = kk * 32 + g * 8 + e;
            int col = t * 16 + c0;
            v[e] = (short)f2bf(scale * src[(size_t)k * 128 + col]);
        }
        *reinterpret_cast<bf16x8*>(ws + dst + (size_t)l * 16) = v;
    } else if (blockIdx.x == 52) {
        float* bias = reinterpret_cast<float*>(ws + 212992);
#pragma unroll
        for (int j = 0; j < 3; ++j) {
            int v = j * 256 + tid;              // 0..767
            int layer = v / 384;
            int r = v % 384;
            int gate = r >> 7;
            int c = r & 127;
            int idx = layer * 128 + c;
            float x;
            if (gate == 0)      x = NEG_L2E * (bWi[idx] + bUi[idx]);
            else if (gate == 1) x = NEG_L2E * (bWo[idx] + bUo[idx]);
            else                x = TWO_L2E * (bWc[idx] + bUc[idx]);
            bias[v] = x;
        }
    }
}

// ---------------------------------------------------------------------------
// One step (L = S>>3, T = S&7).  Per step:
//   issue async stage of S+1 into the OTHER buffer -> per-gate MFMA from the
//   CURRENT buffer -> activation -> per-step reduce (r16 style) -> barrier.
// ---------------------------------------------------------------------------
template<int S>
__device__ __forceinline__ void t_step(
        char* __restrict__ sb0, char* __restrict__ sb1,
        const char* __restrict__ frags,
        bf16x8 (&A0)[4], bf16x8 (&A1)[4],
        unsigned short* __restrict__ slab,
        const float* __restrict__ biasf,
        float (* __restrict__ redbuf)[128],
        int w, int l, int g, int c0) {

    constexpr int L = S >> 3;
    constexpr int T = S & 7;
    char* cur = (S & 1) ? sb1 : sb0;
    char* nxt = (S & 1) ? sb0 : sb1;

    // stage S+1 at top: the whole step (MFMA + act) hides its latency.
    // nxt's last readers were fenced by step S-1's barrier.
    if constexpr (S < 15) {
        const char* gs = frags + 16384 + (size_t)(S + 1) * 12288;
#pragma unroll
        for (int i = 0; i < 3; ++i)
            gload_lds16(gs + (size_t)(i * 4096 + w * 1024) + (size_t)l * 16,
                        nxt + i * 4096 + w * 1024);
    }

    const int c = T * 16 + c0;
    const float Bi = biasf[L * 384 + c];
    const float Bo = biasf[L * 384 + 128 + c];
    const float Bc = biasf[L * 384 + 256 + c];

    const bf16x8 (&A)[4] = (L == 0) ? A0 : A1;
    const char* sr = cur + (size_t)l * 16;

    f32x4 ai = {Bi, Bi, Bi, Bi};
    f32x4 ao = {Bo, Bo, Bo, Bo};
    f32x4 ac = {Bc, Bc, Bc, Bc};
    // per-gate loops: transient weight regs stay tiny (64-reg rung)
#pragma unroll
    for (int kk = 0; kk < 4; ++kk)
        ac = MFMA16(A[kk], *reinterpret_cast<const bf16x8*>(sr + (size_t)(8 + kk) * 1024), ac);
#pragma unroll
    for (int kk = 0; kk < 4; ++kk)
        ai = MFMA16(A[kk], *reinterpret_cast<const bf16x8*>(sr + (size_t)(0 + kk) * 1024), ai);
#pragma unroll
    for (int kk = 0; kk < 4; ++kk)
        ao = MFMA16(A[kk], *reinterpret_cast<const bf16x8*>(sr + (size_t)(4 + kk) * 1024), ao);

    // activation (registers only) — r16-style per-step disposition
    float hsum = 0.0f;
#pragma unroll
    for (int r = 0; r < 4; ++r) {
        float h = act_h(ai[r], ao[r], ac[r]);
        if constexpr (L == 1) {
            hsum += h;
        } else {
            slab[(g * 4 + r) * 40 + (T & 1) * 16 + c0] = f2bf(h);
        }
    }
    if constexpr (L == 0) {
        if constexpr ((T & 1) == 1)   // pair complete -> A1 frag (wave-private DS)
            A1[T >> 1] = *reinterpret_cast<const bf16x8*>(&slab[c0 * 40 + g * 8]);
    } else {
        hsum += __shfl_xor(hsum, 16);
        hsum += __shfl_xor(hsum, 32);
        if (g == 0) redbuf[w][c] = hsum;   // distinct cols per step: no clash
    }

    __syncthreads();   // drains gload (vmcnt) + fences buffer swap
}

// ---------------------------------------------------------------------------
// Main kernel: 2048 blocks x 256 threads; 16 rows/wave; 16 step barriers.
// ---------------------------------------------------------------------------
__global__ __launch_bounds__(256, 8) void tree_enc(
        const float* __restrict__ X,       // [131072][64]
        const float* __restrict__ emb_b,   // [128]
        const char*  __restrict__ frags,   // ws
        float* __restrict__ out) {         // [256][128]

    __shared__ __align__(16) char sbuf0[12288];                // 12288 B
    __shared__ __align__(16) char sbuf1[12288];                // 12288 B
    __shared__ __align__(16) unsigned short slabs[4][16 * 40]; //  5120 B
    __shared__ float redbuf[4][128];                           //  2048 B

    const int tid = threadIdx.x;
    const int w   = tid >> 6;
    const int l   = tid & 63;
    const int g   = l >> 4;
    const int c0  = l & 15;
    const int rowbase = blockIdx.x * 64 + w * 16;
    const int batch   = blockIdx.x >> 3;        // 8 blocks per batch

    unsigned short* __restrict__ slab = slabs[w];
    const float* biasf = reinterpret_cast<const float*>(frags + 212992);

    // -------- async-stage step 0 weights into sbuf0 (overlaps embedding) --
    {
        const char* gs = frags + 16384;
#pragma unroll
        for (int i = 0; i < 3; ++i)
            gload_lds16(gs + (size_t)(i * 4096 + w * 1024) + (size_t)l * 16,
                        sbuf0 + i * 4096 + w * 1024);
    }

    // -------- embedding: h0 for this wave's 16 rows -> slab -> A0 ----------
    bf16x8 A0[4], A1[4];
    {
        bf16x8 afr0, afr1;
        {
            const float* xr = X + (size_t)(rowbase + c0) * 64;
            float4 v0 = *reinterpret_cast<const float4*>(xr + g * 8);
            float4 v1 = *reinterpret_cast<const float4*>(xr + g * 8 + 4);
            float4 v2 = *reinterpret_cast<const float4*>(xr + 32 + g * 8);
            float4 v3 = *reinterpret_cast<const float4*>(xr + 32 + g * 8 + 4);
            afr0 = pack8(v0, v1);
            afr1 = pack8(v2, v3);
        }
#pragma unroll
        for (int t = 0; t < 8; ++t) {
            const char* eb = frags + (size_t)(t * 2) * 1024 + (size_t)l * 16;
            bf16x8 e0 = *reinterpret_cast<const bf16x8*>(eb);
            bf16x8 e1 = *reinterpret_cast<const bf16x8*>(eb + 1024);
            const float be = emb_b[t * 16 + c0];
            f32x4 acc = {be, be, be, be};
            acc = MFMA16(afr0, e0, acc);
            acc = MFMA16(afr1, e1, acc);
#pragma unroll
            for (int r = 0; r < 4; ++r)
                slab[(g * 4 + r) * 40 + (t & 1) * 16 + c0] = f2bf(acc[r]);
            if (t & 1)
                A0[t >> 1] = *reinterpret_cast<const bf16x8*>(&slab[c0 * 40 + g * 8]);
        }
    }
    __syncthreads();   // embedding done AND step-0 staging drained

    // -------- 16 steps, one barrier each --------
    t_step< 0>(sbuf0, sbuf1, frags, A0, A1, slab, biasf, redbuf, w, l, g, c0);
    t_step< 1>(sbuf0, sbuf1, frags, A0, A1, slab, biasf, redbuf, w, l, g, c0);
    t_step< 2>(sbuf0, sbuf1, frags, A0, A1, slab, biasf, redbuf, w, l, g, c0);
    t_step< 3>(sbuf0, sbuf1, frags, A0, A1, slab, biasf, redbuf, w, l, g, c0);
    t_step< 4>(sbuf0, sbuf1, frags, A0, A1, slab, biasf, redbuf, w, l, g, c0);
    t_step< 5>(sbuf0, sbuf1, frags, A0, A1, slab, biasf, redbuf, w, l, g, c0);
    t_step< 6>(sbuf0, sbuf1, frags, A0, A1, slab, biasf, redbuf, w, l, g, c0);
    t_step< 7>(sbuf0, sbuf1, frags, A0, A1, slab, biasf, redbuf, w, l, g, c0);
    t_step< 8>(sbuf0, sbuf1, frags, A0, A1, slab, biasf, redbuf, w, l, g, c0);
    t_step< 9>(sbuf0, sbuf1, frags, A0, A1, slab, biasf, redbuf, w, l, g, c0);
    t_step<10>(sbuf0, sbuf1, frags, A0, A1, slab, biasf, redbuf, w, l, g, c0);
    t_step<11>(sbuf0, sbuf1, frags, A0, A1, slab, biasf, redbuf, w, l, g, c0);
    t_step<12>(sbuf0, sbuf1, frags, A0, A1, slab, biasf, redbuf, w, l, g, c0);
    t_step<13>(sbuf0, sbuf1, frags, A0, A1, slab, biasf, redbuf, w, l, g, c0);
    t_step<14>(sbuf0, sbuf1, frags, A0, A1, slab, biasf, redbuf, w, l, g, c0);
    t_step<15>(sbuf0, sbuf1, frags, A0, A1, slab, biasf, redbuf, w, l, g, c0);

    // -------- block reduce + one atomic per column --------
    if (tid < 128) {
        float s = redbuf[0][tid] + redbuf[1][tid] + redbuf[2][tid] + redbuf[3][tid];
        atomicAdd(&out[batch * 128 + tid], s * (1.0f / 512.0f));
    }
}

// ---------------------------------------------------------------------------
extern "C" void kernel_launch(void* const* d_in, const int* in_sizes, int n_in,
                              void* d_out, int out_size, void* d_ws, size_t ws_size,
                              hipStream_t stream) {
    const float* X    = (const float*)d_in[0];
    const float* embW = (const float*)d_in[1];
    const float* embb = (const float*)d_in[2];
    const float* Wi   = (const float*)d_in[3];
    const float* Wo   = (const float*)d_in[4];
    const float* Wc   = (const float*)d_in[5];
    const float* bWi  = (const float*)d_in[6];
    const float* bUi  = (const float*)d_in[7];
    const float* bWo  = (const float*)d_in[8];
    const float* bUo  = (const float*)d_in[9];
    const float* bWc  = (const float*)d_in[10];
    const float* bUc  = (const float*)d_in[11];
    float* out = (float*)d_out;
    char*  ws  = (char*)d_ws;

    hipMemsetAsync(d_out, 0, (size_t)out_size * sizeof(float), stream);
    prep_frags<<<53, 256, 0, stream>>>(embW, Wi, Wo, Wc,
                                       bWi, bUi, bWo, bUo, bWc, bUc, ws);
    tree_enc<<<2048, 256, 0, stream>>>(X, embb, (const char*)ws, out);
}

// Round 19
// 58.411 us; speedup vs baseline: 1.2302x; 1.0197x over previous
//
#include <hip/hip_runtime.h>

// ---------------------------------------------------------------------------
// TreeEncoder, round 19 = round 16 (best: 52.5us kernel, VGPR=32, 8 blk/CU)
// with ONE isolated change: packed-f32 activation.  The Pade[3/2] rational's
// non-transcendental part (~10 ops/elem) is evaluated on f32x2 pairs so the
// backend can emit VOP3P v_pk_fma/mul/add_f32 -- halves VALU issue for the
// polynomial; the 12 exp2 + 4 rcp per step stay scalar (TRANS can't pack).
//   r18 isolated the barrier change (16 vs 32): neutral-to-worse (residency
//   8->5 blk/CU canceled it) -> r16 structure retained verbatim here:
//   single sbuf + 2 barriers/step, slab transpose, per-step shuffle-reduce,
//   19.4 KB LDS, launch_bounds(256,8).
// ---------------------------------------------------------------------------

typedef short bf16x8 __attribute__((ext_vector_type(8)));
typedef float f32x4  __attribute__((ext_vector_type(4)));
typedef float f32x2  __attribute__((ext_vector_type(2)));

#define MFMA16(a, b, c) __builtin_amdgcn_mfma_f32_16x16x32_bf16((a), (b), (c), 0, 0, 0)

#define NEG_L2E (-1.44269504088896f)
#define TWO_L2E (2.88539008177793f)

__device__ __forceinline__ unsigned short f2bf(float f) {
    return (unsigned short)((__float_as_uint(f) + 0x8000u) >> 16);
}
__device__ __forceinline__ float frcp(float x)  { return __builtin_amdgcn_rcpf(x); }
__device__ __forceinline__ float fexp2(float x) { return __builtin_amdgcn_exp2f(x); }

// packed Pade[3/2] merged activation: 2 elements per call.
//   exp2/rcp scalar (TRANS pipe), polynomial packed (VOP3P).
__device__ __forceinline__ f32x2 act_h2(f32x2 iv, f32x2 ov, f32x2 cv) {
    f32x2 ei = { fexp2(iv.x), fexp2(iv.y) };
    f32x2 eo = { fexp2(ov.x), fexp2(ov.y) };
    f32x2 u  = { fexp2(cv.x), fexp2(cv.y) };
    f32x2 p  = u - 1.0f;
    f32x2 q  = (1.0f + ei) * (u + 1.0f);     // cc = p/q = sig(i)*tanh(c~)
    f32x2 p2 = p * p, q2 = q * q;
    f32x2 t15 = 15.0f * q2;
    f32x2 pn  = p * (t15 + p2);
    f32x2 qd  = (q * (6.0f * p2 + t15)) * (1.0f + eo);
    return pn * f32x2{ frcp(qd.x), frcp(qd.y) };
}

__device__ __forceinline__ bf16x8 pack8(float4 v0, float4 v1) {
    bf16x8 a;
    a[0] = (short)f2bf(v0.x); a[1] = (short)f2bf(v0.y);
    a[2] = (short)f2bf(v0.z); a[3] = (short)f2bf(v0.w);
    a[4] = (short)f2bf(v1.x); a[5] = (short)f2bf(v1.y);
    a[6] = (short)f2bf(v1.z); a[7] = (short)f2bf(v1.w);
    return a;
}

// async global->LDS, 16B/lane; LDS dest = wave-uniform base + lane*16
__device__ __forceinline__ void gload_lds16(const void* gsrc, void* ldst) {
    __builtin_amdgcn_global_load_lds(
        (const __attribute__((address_space(1))) unsigned int*)gsrc,
        (__attribute__((address_space(3))) unsigned int*)ldst, 16, 0, 0);
}

// ---------------------------------------------------------------------------
// Prep (53 blocks x 256): ws layout identical to rounds 8-18.
//   [0,16384) emb frags; [16384,212992) gate frags; [212992,216064) biases.
// ---------------------------------------------------------------------------
__global__ void prep_frags(const float* __restrict__ embW,
                           const float* __restrict__ Wi,
                           const float* __restrict__ Wo,
                           const float* __restrict__ Wc,
                           const float* __restrict__ bWi, const float* __restrict__ bUi,
                           const float* __restrict__ bWo, const float* __restrict__ bUo,
                           const float* __restrict__ bWc, const float* __restrict__ bUc,
                           char* __restrict__ ws) {
    const int tid = threadIdx.x;
    const int fb  = blockIdx.x * 4 + (tid >> 6);
    const int l   = tid & 63;

    if (fb < 208) {
        int g  = l >> 4, c0 = l & 15;
        const float* src;
        int t, kk;
        size_t dst;
        float scale;
        if (fb < 16) {
            t = fb >> 1; kk = fb & 1;
            src = embW;                                   // [64][128]
            dst = (size_t)fb * 1024;
            scale = 1.0f;
        } else {
            int r = fb - 16;                              // (layer*8+t)*12+gate*4+kk
            int layer = r / 96;
            int r2 = r % 96;
            t = r2 / 12;
            int r3 = r2 % 12;
            int gate = r3 >> 2;
            kk = r3 & 3;
            const float* Ws[3] = {Wi, Wo, Wc};
            src = Ws[gate] + (size_t)layer * 128 * 128;   // [128][128]
            dst = 16384 + (size_t)r * 1024;
            scale = (gate == 2) ? TWO_L2E : NEG_L2E;
        }
        bf16x8 v;
#pragma unroll
        for (int e = 0; e < 8; ++e) {
            int k   = kk * 32 + g * 8 + e;
            int col = t * 16 + c0;
            v[e] = (short)f2bf(scale * src[(size_t)k * 128 + col]);
        }
        *reinterpret_cast<bf16x8*>(ws + dst + (size_t)l * 16) = v;
    } else if (blockIdx.x == 52) {
        float* bias = reinterpret_cast<float*>(ws + 212992);
#pragma unroll
        for (int j = 0; j < 3; ++j) {
            int v = j * 256 + tid;              // 0..767
            int layer = v / 384;
            int r = v % 384;
            int gate = r >> 7;
            int c = r & 127;
            int idx = layer * 128 + c;
            float x;
            if (gate == 0)      x = NEG_L2E * (bWi[idx] + bUi[idx]);
            else if (gate == 1) x = NEG_L2E * (bWo[idx] + bUo[idx]);
            else                x = TWO_L2E * (bWc[idx] + bUc[idx]);
            bias[v] = x;
        }
    }
}

// ---------------------------------------------------------------------------
// One step (L = S>>3, T = S&7).  Per step (r16 structure):
//   per-gate MFMA from sbuf -> barrier -> async-stage S+1 (global_load_lds)
//   -> packed activation (covers stage latency) -> barrier.
// ---------------------------------------------------------------------------
template<int S>
__device__ __forceinline__ void t_step(
        char* __restrict__ sbuf,
        const char* __restrict__ frags,
        bf16x8 (&A0)[4], bf16x8 (&A1)[4],
        unsigned short* __restrict__ slab,
        const float* __restrict__ biasf,
        float (* __restrict__ redbuf)[128],
        int w, int l, int g, int c0) {

    constexpr int L = S >> 3;
    constexpr int T = S & 7;
    const int c = T * 16 + c0;
    const float Bi = biasf[L * 384 + c];
    const float Bo = biasf[L * 384 + 128 + c];
    const float Bc = biasf[L * 384 + 256 + c];

    const bf16x8 (&A)[4] = (L == 0) ? A0 : A1;
    const char* sr = sbuf + (size_t)l * 16;

    f32x4 ai = {Bi, Bi, Bi, Bi};
    f32x4 ao = {Bo, Bo, Bo, Bo};
    f32x4 ac = {Bc, Bc, Bc, Bc};
    // per-gate loops: transient weight regs stay tiny (64-reg rung)
#pragma unroll
    for (int kk = 0; kk < 4; ++kk)
        ac = MFMA16(A[kk], *reinterpret_cast<const bf16x8*>(sr + (size_t)(8 + kk) * 1024), ac);
#pragma unroll
    for (int kk = 0; kk < 4; ++kk)
        ai = MFMA16(A[kk], *reinterpret_cast<const bf16x8*>(sr + (size_t)(0 + kk) * 1024), ai);
#pragma unroll
    for (int kk = 0; kk < 4; ++kk)
        ao = MFMA16(A[kk], *reinterpret_cast<const bf16x8*>(sr + (size_t)(4 + kk) * 1024), ao);

    __syncthreads();                 // all waves done reading sbuf for step S

    if (S < 15) {                    // async-stage step S+1 (no VGPRs)
        const char* gs = frags + 16384 + (size_t)(S + 1) * 12288;
#pragma unroll
        for (int i = 0; i < 3; ++i)
            gload_lds16(gs + (size_t)(i * 4096 + w * 1024) + (size_t)l * 16,
                        sbuf + i * 4096 + w * 1024);
    }

    // packed activation — covers the staging latency
    f32x2 h01 = act_h2(f32x2{ai[0], ai[1]}, f32x2{ao[0], ao[1]}, f32x2{ac[0], ac[1]});
    f32x2 h23 = act_h2(f32x2{ai[2], ai[3]}, f32x2{ao[2], ao[3]}, f32x2{ac[2], ac[3]});
    if constexpr (L == 1) {
        float hsum = (h01.x + h01.y) + (h23.x + h23.y);
        hsum += __shfl_xor(hsum, 16);
        hsum += __shfl_xor(hsum, 32);
        if (g == 0) redbuf[w][c] = hsum;   // distinct cols per step: no clash
    } else {
        slab[(g * 4 + 0) * 40 + (T & 1) * 16 + c0] = f2bf(h01.x);
        slab[(g * 4 + 1) * 40 + (T & 1) * 16 + c0] = f2bf(h01.y);
        slab[(g * 4 + 2) * 40 + (T & 1) * 16 + c0] = f2bf(h23.x);
        slab[(g * 4 + 3) * 40 + (T & 1) * 16 + c0] = f2bf(h23.y);
        if constexpr ((T & 1) == 1)   // pair complete -> A1 frag (wave-private DS)
            A1[T >> 1] = *reinterpret_cast<const bf16x8*>(&slab[c0 * 40 + g * 8]);
    }

    if (S < 15) __syncthreads();     // staged sbuf visible for step S+1
}

// ---------------------------------------------------------------------------
// Main kernel: 2048 blocks x 256 threads; 16 rows/wave; 8 blocks/CU.
// ---------------------------------------------------------------------------
__global__ __launch_bounds__(256, 8) void tree_enc(
        const float* __restrict__ X,       // [131072][64]
        const float* __restrict__ emb_b,   // [128]
        const char*  __restrict__ frags,   // ws
        float* __restrict__ out) {         // [256][128]

    __shared__ __align__(16) char sbuf[12288];                 // 12288 B
    __shared__ __align__(16) unsigned short slabs[4][16 * 40]; //  5120 B
    __shared__ float redbuf[4][128];                           //  2048 B

    const int tid = threadIdx.x;
    const int w   = tid >> 6;
    const int l   = tid & 63;
    const int g   = l >> 4;
    const int c0  = l & 15;
    const int rowbase = blockIdx.x * 64 + w * 16;
    const int batch   = blockIdx.x >> 3;        // 8 blocks per batch

    unsigned short* __restrict__ slab = slabs[w];
    const float* biasf = reinterpret_cast<const float*>(frags + 212992);

    // -------- async-stage step 0 weights (overlaps the whole embedding) ----
    {
        const char* gs = frags + 16384;
#pragma unroll
        for (int i = 0; i < 3; ++i)
            gload_lds16(gs + (size_t)(i * 4096 + w * 1024) + (size_t)l * 16,
                        sbuf + i * 4096 + w * 1024);
    }

    // -------- embedding: h0 for this wave's 16 rows -> slab -> A0 ----------
    bf16x8 A0[4], A1[4];
    {
        bf16x8 afr0, afr1;
        {
            const float* xr = X + (size_t)(rowbase + c0) * 64;
            float4 v0 = *reinterpret_cast<const float4*>(xr + g * 8);
            float4 v1 = *reinterpret_cast<const float4*>(xr + g * 8 + 4);
            float4 v2 = *reinterpret_cast<const float4*>(xr + 32 + g * 8);
            float4 v3 = *reinterpret_cast<const float4*>(xr + 32 + g * 8 + 4);
            afr0 = pack8(v0, v1);
            afr1 = pack8(v2, v3);
        }
#pragma unroll
        for (int t = 0; t < 8; ++t) {
            const char* eb = frags + (size_t)(t * 2) * 1024 + (size_t)l * 16;
            bf16x8 e0 = *reinterpret_cast<const bf16x8*>(eb);
            bf16x8 e1 = *reinterpret_cast<const bf16x8*>(eb + 1024);
            const float be = emb_b[t * 16 + c0];
            f32x4 acc = {be, be, be, be};
            acc = MFMA16(afr0, e0, acc);
            acc = MFMA16(afr1, e1, acc);
#pragma unroll
            for (int r = 0; r < 4; ++r)
                slab[(g * 4 + r) * 40 + (t & 1) * 16 + c0] = f2bf(acc[r]);
            if (t & 1)
                A0[t >> 1] = *reinterpret_cast<const bf16x8*>(&slab[c0 * 40 + g * 8]);
        }
    }
    __syncthreads();   // embedding done AND step-0 staging drained (vmcnt)

    // -------- 16 steps --------
    t_step< 0>(sbuf, frags, A0, A1, slab, biasf, redbuf, w, l, g, c0);
    t_step< 1>(sbuf, frags, A0, A1, slab, biasf, redbuf, w, l, g, c0);
    t_step< 2>(sbuf, frags, A0, A1, slab, biasf, redbuf, w, l, g, c0);
    t_step< 3>(sbuf, frags, A0, A1, slab, biasf, redbuf, w, l, g, c0);
    t_step< 4>(sbuf, frags, A0, A1, slab, biasf, redbuf, w, l, g, c0);
    t_step< 5>(sbuf, frags, A0, A1, slab, biasf, redbuf, w, l, g, c0);
    t_step< 6>(sbuf, frags, A0, A1, slab, biasf, redbuf, w, l, g, c0);
    t_step< 7>(sbuf, frags, A0, A1, slab, biasf, redbuf, w, l, g, c0);
    t_step< 8>(sbuf, frags, A0, A1, slab, biasf, redbuf, w, l, g, c0);
    t_step< 9>(sbuf, frags, A0, A1, slab, biasf, redbuf, w, l, g, c0);
    t_step<10>(sbuf, frags, A0, A1, slab, biasf, redbuf, w, l, g, c0);
    t_step<11>(sbuf, frags, A0, A1, slab, biasf, redbuf, w, l, g, c0);
    t_step<12>(sbuf, frags, A0, A1, slab, biasf, redbuf, w, l, g, c0);
    t_step<13>(sbuf, frags, A0, A1, slab, biasf, redbuf, w, l, g, c0);
    t_step<14>(sbuf, frags, A0, A1, slab, biasf, redbuf, w, l, g, c0);
    t_step<15>(sbuf, frags, A0, A1, slab, biasf, redbuf, w, l, g, c0);

    // -------- block reduce + one atomic per column --------
    __syncthreads();
    if (tid < 128) {
        float s = redbuf[0][tid] + redbuf[1][tid] + redbuf[2][tid] + redbuf[3][tid];
        atomicAdd(&out[batch * 128 + tid], s * (1.0f / 512.0f));
    }
}

// ---------------------------------------------------------------------------
extern "C" void kernel_launch(void* const* d_in, const int* in_sizes, int n_in,
                              void* d_out, int out_size, void* d_ws, size_t ws_size,
                              hipStream_t stream) {
    const float* X    = (const float*)d_in[0];
    const float* embW = (const float*)d_in[1];
    const float* embb = (const float*)d_in[2];
    const float* Wi   = (const float*)d_in[3];
    const float* Wo   = (const float*)d_in[4];
    const float* Wc   = (const float*)d_in[5];
    const float* bWi  = (const float*)d_in[6];
    const float* bUi  = (const float*)d_in[7];
    const float* bWo  = (const float*)d_in[8];
    const float* bUo  = (const float*)d_in[9];
    const float* bWc  = (const float*)d_in[10];
    const float* bUc  = (const float*)d_in[11];
    float* out = (float*)d_out;
    char*  ws  = (char*)d_ws;

    hipMemsetAsync(d_out, 0, (size_t)out_size * sizeof(float), stream);
    prep_frags<<<53, 256, 0, stream>>>(embW, Wi, Wo, Wc,
                                       bWi, bUi, bWo, bUo, bWc, bUc, ws);
    tree_enc<<<2048, 256, 0, stream>>>(X, embb, (const char*)ws, out);
}